// Round 7
// baseline (558.115 us; speedup 1.0000x reference)
//
#include <hip/hip_runtime.h>

#define BATCH 8192
#define SEQ 512
#define INND 5
#define HID 64
#define STRIDE 104  // shorts per LDS row; 52 dwords ≡ 20 mod 32: odd-multiplier
                    // rotation -> row-major reads are bank-uniform WITHOUT swizzle.

typedef __attribute__((ext_vector_type(8))) short short8;
typedef __attribute__((ext_vector_type(4))) float f32x4;
typedef __attribute__((ext_vector_type(2))) float f32x2;

__device__ __forceinline__ unsigned short f2bf(float f) {
  union { float f; unsigned u; } v; v.f = f;
  unsigned r = v.u + 0x7FFFu + ((v.u >> 16) & 1u);
  return (unsigned short)(r >> 16);
}
__device__ __forceinline__ float bf2f(unsigned short s) {
  union { unsigned u; float f; } v; v.u = ((unsigned)s) << 16;
  return v.f;
}
#define RCP(x) __builtin_amdgcn_rcpf(x)

__device__ __forceinline__ f32x2 mk2(float a, float b) {
  f32x2 r; r.x = a; r.y = b; return r;
}

// Padé(7,6) of tanh: p/q, |err| <= ~1e-4 on |x|<=4.9 (clamped), p/q < 1 there.
__device__ __forceinline__ void pade_tanh(f32x2 x, f32x2& p, f32x2& q) {
  const f32x2 x2 = x * x;
  f32x2 t = x2 + 378.f;
  t = t * x2 + 17325.f;
  t = t * x2 + 135135.f;
  p = t * x;
  f32x2 u = x2 * 28.f + 3150.f;
  u = u * x2 + 62370.f;
  q = u * x2 + 135135.f;
}
__device__ __forceinline__ f32x2 clamp2(f32x2 v) {
  f32x2 r;
  r.x = fminf(fmaxf(v.x, -4.9f), 4.9f);  // -> v_med3_f32
  r.y = fminf(fmaxf(v.y, -4.9f), 4.9f);
  return r;
}

// One WG (4 waves) owns 16 batch rows. Operand-swapped MFMA: D = W_cat · H^T;
// thread (w,kg,q,l15) owns gate[64X+16w+4kg+q][batch=l15] -> 4 consecutive
// hidden h outputs -> one b64 LDS write at column 16w+4kg.
// W rows pre-scaled: i,f,o by 0.5 (sigma(z) = (1+tanh(z/2))/2), g by 1.0.
// All gate nonlinearities via Pade(7,6) rational tanh: 2 rcp/element, 0 exp.
// K-extension: k 0..63 = h, 64..68 = x_t, 69 = 1.0 (bias), rest 0.
__global__ __launch_bounds__(256) void lstm_kernel(
    const float* __restrict__ inputs, const float* __restrict__ W_ih,
    const float* __restrict__ W_hh, const float* __restrict__ b_ih,
    const float* __restrict__ b_hh, const float* __restrict__ fc_w,
    const float* __restrict__ fc_b, float* __restrict__ out) {
  __shared__ unsigned short hbuf[2][16][STRIDE] __attribute__((aligned(16)));

  const int tid = threadIdx.x;
  const int lane = tid & 63;
  const int w = tid >> 6;    // wave 0..3
  const int l15 = lane & 15; // batch row (local)
  const int kg = lane >> 4;  // k-group / D row-group
  const int b0 = blockIdx.x * 16;

  // ---------------- W_cat fragments (registers), tanh-half-scaled ----------
  short8 wf[4][3];
#pragma unroll
  for (int X = 0; X < 4; ++X) {
    const float sc = (X == 2) ? 1.f : 0.5f;
    const int col = 64 * X + 16 * w + l15;
    const float* wr = W_hh + col * 64;
#pragma unroll
    for (int s = 0; s < 2; ++s) {
      const float* p = wr + 32 * s + 8 * kg;
      short8 v;
#pragma unroll
      for (int j = 0; j < 8; ++j) v[j] = (short)f2bf(sc * p[j]);
      wf[X][s] = v;
    }
    short8 e;
#pragma unroll
    for (int j = 0; j < 8; ++j) e[j] = 0;
    if (kg == 0) {  // k = 64..71
#pragma unroll
      for (int j = 0; j < 5; ++j) e[j] = (short)f2bf(sc * W_ih[col * 5 + j]);
      e[5] = (short)f2bf(sc * (b_ih[col] + b_hh[col]));  // pairs with const 1.0
    }
    wf[X][2] = e;
  }

  // ------------- per-thread LDS indices (round-1 proven pattern) -----------
  unsigned short* const hb0 = &hbuf[0][0][0];
  const int rd0 = l15 * STRIDE + 8 * kg;  // k = 8kg..8kg+7
  const int rd1 = rd0 + 32;               // k = 32+8kg
  const int rd2 = rd0 + 64;               // k = 64+8kg
  const int hwr = l15 * STRIDE + 16 * w + 4 * kg;  // 4 consecutive h (b64)

  // ---------------- x writer lanes ----------------
  const bool writer = (tid < 16 * INND);  // 80 lanes: (row,i)
  const int wrow = tid / INND;
  const int wi = tid - wrow * INND;
  const float* xptr = inputs + (size_t)(b0 + wrow) * (SEQ * INND) + wi;
  const int xcol = 64 + wi;

  // ---------------- LDS init ----------------
  for (int i = tid; i < 2 * 16 * STRIDE; i += 256) hb0[i] = 0;
  __syncthreads();
  if (tid < 32) hbuf[tid >> 4][tid & 15][69] = 0x3F80;  // constant-1 column
  float x_next = 0.f;
  if (writer) {
    hbuf[0][wrow][xcol] = f2bf(xptr[0]);
    x_next = xptr[INND];
  }
  __syncthreads();

  const f32x4 Z = {0.f, 0.f, 0.f, 0.f};

  // ---------------- recurrence ----------------
  f32x2 cst[2] = {{0.f, 0.f}, {0.f, 0.f}};
  for (int t = 0; t < SEQ; ++t) {
    const int nxt = (t & 1) ^ 1;

    float x_n2 = 0.f;
    if (writer && t + 2 < SEQ) x_n2 = xptr[(t + 2) * INND];

    const unsigned short* hc = hb0 + (t & 1) * (16 * STRIDE);
    f32x4 acc0, acc1, acc2, acc3;
    {
      const short8 a0 = *(const short8*)(hc + rd0);
      acc0 = __builtin_amdgcn_mfma_f32_16x16x32_bf16(wf[0][0], a0, Z, 0, 0, 0);
      acc1 = __builtin_amdgcn_mfma_f32_16x16x32_bf16(wf[1][0], a0, Z, 0, 0, 0);
      acc2 = __builtin_amdgcn_mfma_f32_16x16x32_bf16(wf[2][0], a0, Z, 0, 0, 0);
      acc3 = __builtin_amdgcn_mfma_f32_16x16x32_bf16(wf[3][0], a0, Z, 0, 0, 0);
      const short8 a1 = *(const short8*)(hc + rd1);
      acc0 = __builtin_amdgcn_mfma_f32_16x16x32_bf16(wf[0][1], a1, acc0, 0, 0, 0);
      acc1 = __builtin_amdgcn_mfma_f32_16x16x32_bf16(wf[1][1], a1, acc1, 0, 0, 0);
      acc2 = __builtin_amdgcn_mfma_f32_16x16x32_bf16(wf[2][1], a1, acc2, 0, 0, 0);
      acc3 = __builtin_amdgcn_mfma_f32_16x16x32_bf16(wf[3][1], a1, acc3, 0, 0, 0);
      const short8 a2 = *(const short8*)(hc + rd2);
      acc0 = __builtin_amdgcn_mfma_f32_16x16x32_bf16(wf[0][2], a2, acc0, 0, 0, 0);
      acc1 = __builtin_amdgcn_mfma_f32_16x16x32_bf16(wf[1][2], a2, acc1, 0, 0, 0);
      acc2 = __builtin_amdgcn_mfma_f32_16x16x32_bf16(wf[2][2], a2, acc2, 0, 0, 0);
      acc3 = __builtin_amdgcn_mfma_f32_16x16x32_bf16(wf[3][2], a2, acc3, 0, 0, 0);
    }

    // acc0=zi/2, acc1=zf/2, acc2=zg, acc3=zo/2
    unsigned pk[2];
#pragma unroll
    for (int p = 0; p < 2; ++p) {
      const f32x2 xi = clamp2(mk2(acc0[2 * p], acc0[2 * p + 1]));
      const f32x2 xf = clamp2(mk2(acc1[2 * p], acc1[2 * p + 1]));
      const f32x2 xg = clamp2(mk2(acc2[2 * p], acc2[2 * p + 1]));
      const f32x2 xo = clamp2(mk2(acc3[2 * p], acc3[2 * p + 1]));
      f32x2 pi, qi, pf, qf, pg, qg, po, qo;
      pade_tanh(xi, pi, qi);
      pade_tanh(xf, pf, qf);
      pade_tanh(xg, pg, qg);
      pade_tanh(xo, po, qo);
      const f32x2 si = qi + pi;  // 2*sigmoid(zi)*qi
      const f32x2 sf = qf + pf;
      const f32x2 so = qo + po;
      // c = 0.5*[sf*c*qi*qg + si*pg*qf] / (qf*qi*qg)
      const f32x2 qiqg = qi * qg;
      const f32x2 numc = (sf * cst[p]) * qiqg + (si * pg) * qf;
      const f32x2 denc = qf * qiqg;
      f32x2 Rc; Rc.x = RCP(denc.x); Rc.y = RCP(denc.y);
      const f32x2 c = (0.5f * numc) * Rc;
      cst[p] = c;
      // h = 0.5*so*pc / (qo*qc)
      f32x2 pc, qc;
      pade_tanh(clamp2(c), pc, qc);
      const f32x2 numh = (so * pc) * 0.5f;
      const f32x2 denh = qo * qc;
      f32x2 Rh; Rh.x = RCP(denh.x); Rh.y = RCP(denh.y);
      const f32x2 h = numh * Rh;
      asm("v_cvt_pk_bf16_f32 %0, %1, %2" : "=v"(pk[p]) : "v"(h.x), "v"(h.y));
    }
    {
      uint2 pkv; pkv.x = pk[0]; pkv.y = pk[1];
      *(uint2*)(hb0 + nxt * (16 * STRIDE) + hwr) = pkv;  // 4 bf16 h, one b64
    }
    if (writer && t + 1 < SEQ) hbuf[nxt][wrow][xcol] = f2bf(x_next);
    x_next = x_n2;
    __syncthreads();
  }

  // ---------------- epilogue: out = leaky_relu(h @ fc_w^T + fc_b) ----------
  if (tid < 64) {
    const int row = tid >> 2, seg = tid & 3;
    float sum = 0.f;
#pragma unroll
    for (int j = 0; j < 16; ++j)
      sum += bf2f(hbuf[0][row][seg * 16 + j]) * fc_w[seg * 16 + j];
    sum += __shfl_xor(sum, 1);
    sum += __shfl_xor(sum, 2);
    if (seg == 0) {
      const float p = sum + fc_b[0];
      out[b0 + row] = p > 0.f ? p : 0.01f * p;
    }
  }
}

extern "C" void kernel_launch(void* const* d_in, const int* in_sizes, int n_in,
                              void* d_out, int out_size, void* d_ws, size_t ws_size,
                              hipStream_t stream) {
  const float* inputs = (const float*)d_in[0];
  const float* W_ih = (const float*)d_in[1];
  const float* W_hh = (const float*)d_in[2];
  const float* b_ih = (const float*)d_in[3];
  const float* b_hh = (const float*)d_in[4];
  const float* fc_w = (const float*)d_in[5];
  const float* fc_b = (const float*)d_in[6];
  float* out = (float*)d_out;

  lstm_kernel<<<BATCH / 16, 256, 0, stream>>>(inputs, W_ih, W_hh, b_ih, b_hh,
                                              fc_w, fc_b, out);
}